// Round 1
// 4757.430 us; speedup vs baseline: 2.3618x; 2.3618x over previous
//
#include <hip/hip_runtime.h>
#include <hip/hip_fp16.h>
#include <cstdint>
#include <cstddef>

#define BATCH 2
#define SEQ   2048
#define DMOD  2304
#define NHQ   8
#define NHKV  4
#define HDIM  256
#define FDIM  9216
#define NROWS (BATCH*SEQ)   // 4096

typedef unsigned short u16;
typedef unsigned int   u32;
typedef __attribute__((ext_vector_type(4))) unsigned short us4;
typedef __attribute__((ext_vector_type(8))) short s8v;
typedef __attribute__((ext_vector_type(4))) float f4v;
typedef __attribute__((ext_vector_type(4))) _Float16 h4v;
typedef __attribute__((ext_vector_type(8))) _Float16 h8v;

__device__ __forceinline__ u16 f2bf(float f) {
  u32 u = __builtin_bit_cast(u32, f);
  u32 r = (u + 0x7fffu + ((u >> 16) & 1u)) >> 16;
  return (u16)r;
}
__device__ __forceinline__ float bf2f(u16 h) {
  u32 u = ((u32)h) << 16;
  return __builtin_bit_cast(float, u);
}
__device__ __forceinline__ u16 f2h(float f) {
  _Float16 h = (_Float16)f;
  return __builtin_bit_cast(u16, h);
}
__device__ __forceinline__ float fast_tanh(float t) {
  t = fminf(fmaxf(t, -10.f), 10.f);
  float e = __expf(t + t);
  return (e - 1.f) * __builtin_amdgcn_rcpf(e + 1.f);
}

// ---------------- GEMM: A bf16 (M=4096 x K row-major), B f32 (K x N row-major),
// inline f32->bf16 staging, 128x128 tile, BK=32, 16x16x32 bf16 MFMA ----------
#define LDSTR 40   // 32 + 8 pad (80B rows -> 20-bank rotation, 2-way max = free)

__device__ __forceinline__ void stage_A(const u16* __restrict__ A, u16* As, int K, int m0, int k0, int tid) {
  int c = tid;
  #pragma unroll
  for (int cc = 0; cc < 2; ++cc, c += 256) {
    int row = c >> 2, kc = c & 3;
    const u16* src = A + (size_t)(m0 + row) * K + k0 + kc * 8;
    us4 v0 = *(const us4*)src;
    us4 v1 = *(const us4*)(src + 4);
    u16* dst = As + row * LDSTR + kc * 8;
    *(us4*)dst = v0;
    *(us4*)(dst + 4) = v1;
  }
}

__device__ __forceinline__ void stage_B(const float* __restrict__ B, u16* Bs, int N, int k0, int n0, int tid) {
  int nn = tid & 127, kh = tid >> 7;
  const float* src = B + (size_t)(k0 + kh * 16) * N + n0 + nn;
  u16 tmp[16];
  #pragma unroll
  for (int j = 0; j < 16; ++j) tmp[j] = f2bf(src[(size_t)j * N]);
  u16* dst = Bs + nn * LDSTR + kh * 16;
  #pragma unroll
  for (int j4 = 0; j4 < 4; ++j4) {
    us4 v = { tmp[j4*4+0], tmp[j4*4+1], tmp[j4*4+2], tmp[j4*4+3] };
    *(us4*)(dst + j4 * 4) = v;
  }
}

__device__ __forceinline__ s8v frag_load(const u16* p) {
  union { us4 h[2]; s8v v; } u;
  u.h[0] = *(const us4*)p;
  u.h[1] = *(const us4*)(p + 4);
  return u.v;
}

// EPI 0: f32 plain row-major out.
// EPI 1: fp16 out in (B, H=N/256, S, 256) attn layout, *scale.
// EPI 2: fp16 out TRANSPOSED (B, H=N/256, HD=256, S) layout (for V in PV mfma), *scale.
template<int EPI>
__global__ __launch_bounds__(256) void gemm_k(const u16* __restrict__ A, const float* __restrict__ B,
                                              void* __restrict__ C, int N, int K, float scale)
{
  __shared__ u16 As[128 * LDSTR];
  __shared__ u16 Bs[128 * LDSTR];
  int tid = threadIdx.x;
  int mt = blockIdx.x & 31, nt = blockIdx.x >> 5;   // M fixed = 4096 -> 32 m-tiles, mt fastest (B-panel reuse)
  int m0 = mt << 7, n0 = nt << 7;
  int lane = tid & 63, wid = tid >> 6;
  int wrow = wid >> 1, wcol = wid & 1;
  int lrow = lane & 15, quad = lane >> 4;
  f4v acc[4][4] = {};
  for (int k0 = 0; k0 < K; k0 += 32) {
    __syncthreads();
    stage_A(A, As, K, m0, k0, tid);
    stage_B(B, Bs, N, k0, n0, tid);
    __syncthreads();
    s8v af[4], bfv[4];
    #pragma unroll
    for (int i = 0; i < 4; ++i)
      af[i] = frag_load(As + (wrow*64 + i*16 + lrow) * LDSTR + quad * 8);
    #pragma unroll
    for (int j = 0; j < 4; ++j)
      bfv[j] = frag_load(Bs + (wcol*64 + j*16 + lrow) * LDSTR + quad * 8);
    #pragma unroll
    for (int i = 0; i < 4; ++i)
      #pragma unroll
      for (int j = 0; j < 4; ++j)
        acc[i][j] = __builtin_amdgcn_mfma_f32_16x16x32_bf16(af[i], bfv[j], acc[i][j], 0, 0, 0);
  }
  #pragma unroll
  for (int i = 0; i < 4; ++i) {
    #pragma unroll
    for (int j = 0; j < 4; ++j) {
      int col = n0 + wcol*64 + j*16 + lrow;
      int row0 = m0 + wrow*64 + i*16 + (quad << 2);   // C/D: col=lane&15, row=quad*4+reg (m89)
      if (EPI == 2) {
        h4v o;
        #pragma unroll
        for (int r = 0; r < 4; ++r) o[r] = (_Float16)(acc[i][j][r] * scale);
        int bb = row0 >> 11, s = row0 & 2047;
        int hh = col >> 8, hd = col & 255;
        *(h4v*)&((_Float16*)C)[((((size_t)bb * (N >> 8) + hh) * HDIM + hd) << 11) + s] = o;
      } else {
        #pragma unroll
        for (int r = 0; r < 4; ++r) {
          int row = row0 + r;
          float val = acc[i][j][r] * scale;
          if (EPI == 0) {
            ((float*)C)[(size_t)row * N + col] = val;
          } else {
            int b = row >> 11, s = row & 2047, hh = col >> 8, hd = col & 255;
            ((_Float16*)C)[((((size_t)b * (N >> 8) + hh) * SEQ + s) << 8) + hd] = (_Float16)val;
          }
        }
      }
    }
  }
}

// dual-B GEMM for FFW: C = bf16( gelu_tanh(A@B0) * (A@B1) ), plain row-major
__global__ __launch_bounds__(256) void gemm_dual_k(const u16* __restrict__ A, const float* __restrict__ B0,
                                                   const float* __restrict__ B1, u16* __restrict__ C,
                                                   int N, int K)
{
  __shared__ u16 As[128 * LDSTR];
  __shared__ u16 B0s[128 * LDSTR];
  __shared__ u16 B1s[128 * LDSTR];
  int tid = threadIdx.x;
  int mt = blockIdx.x & 31, nt = blockIdx.x >> 5;
  int m0 = mt << 7, n0 = nt << 7;
  int lane = tid & 63, wid = tid >> 6;
  int wrow = wid >> 1, wcol = wid & 1;
  int lrow = lane & 15, quad = lane >> 4;
  f4v acc0[4][4] = {}, acc1[4][4] = {};
  for (int k0 = 0; k0 < K; k0 += 32) {
    __syncthreads();
    stage_A(A, As, K, m0, k0, tid);
    stage_B(B0, B0s, N, k0, n0, tid);
    stage_B(B1, B1s, N, k0, n0, tid);
    __syncthreads();
    s8v af[4], b0v[4], b1v[4];
    #pragma unroll
    for (int i = 0; i < 4; ++i)
      af[i] = frag_load(As + (wrow*64 + i*16 + lrow) * LDSTR + quad * 8);
    #pragma unroll
    for (int j = 0; j < 4; ++j) {
      b0v[j] = frag_load(B0s + (wcol*64 + j*16 + lrow) * LDSTR + quad * 8);
      b1v[j] = frag_load(B1s + (wcol*64 + j*16 + lrow) * LDSTR + quad * 8);
    }
    #pragma unroll
    for (int i = 0; i < 4; ++i)
      #pragma unroll
      for (int j = 0; j < 4; ++j) {
        acc0[i][j] = __builtin_amdgcn_mfma_f32_16x16x32_bf16(af[i], b0v[j], acc0[i][j], 0, 0, 0);
        acc1[i][j] = __builtin_amdgcn_mfma_f32_16x16x32_bf16(af[i], b1v[j], acc1[i][j], 0, 0, 0);
      }
  }
  #pragma unroll
  for (int i = 0; i < 4; ++i) {
    #pragma unroll
    for (int j = 0; j < 4; ++j) {
      int col = n0 + wcol*64 + j*16 + lrow;
      #pragma unroll
      for (int r = 0; r < 4; ++r) {
        int row = m0 + wrow*64 + i*16 + (quad << 2) + r;
        float x = acc0[i][j][r];
        float g = 0.5f * x * (1.f + fast_tanh(0.7978845608028654f * (x + 0.044715f * x * x * x)));
        C[(size_t)row * N + col] = f2bf(g * acc1[i][j][r]);
      }
    }
  }
}

// ---------------- RMS / fuse / rope ----------------

__global__ __launch_bounds__(256) void rms_bf16_k(const float* __restrict__ x, const float* __restrict__ w,
                                                  u16* __restrict__ h)
{
  __shared__ float sbuf[4];
  int r = blockIdx.x, tid = threadIdx.x;
  int lane = tid & 63, wid = tid >> 6;
  const float* xr = x + (size_t)r * DMOD;
  float v[9]; float ss = 0.f;
  #pragma unroll
  for (int j = 0; j < 9; ++j) { v[j] = xr[tid + j*256]; ss += v[j]*v[j]; }
  #pragma unroll
  for (int off = 32; off > 0; off >>= 1) ss += __shfl_xor(ss, off);
  if (lane == 0) sbuf[wid] = ss;
  __syncthreads();
  float sc = rsqrtf((sbuf[0]+sbuf[1]+sbuf[2]+sbuf[3]) * (1.f/2304.f) + 1e-6f);
  #pragma unroll
  for (int j = 0; j < 9; ++j) {
    int d = tid + j*256;
    h[(size_t)r * DMOD + d] = f2bf(v[j] * sc * w[d]);
  }
}

// x1 = xin + rms(proj, wpost); write x1 -> xout (f32); if wnext: hout = bf16(rms(x1, wnext))
__global__ __launch_bounds__(256) void fuse_k(const float* __restrict__ proj, const float* __restrict__ xin,
                                              float* __restrict__ xout, const float* __restrict__ wpost,
                                              const float* __restrict__ wnext, u16* __restrict__ hout)
{
  __shared__ float sbuf[4];
  int r = blockIdx.x, tid = threadIdx.x;
  int lane = tid & 63, wid = tid >> 6;
  const float* pr = proj + (size_t)r * DMOD;
  const float* xr = xin + (size_t)r * DMOD;
  float p[9]; float ss = 0.f;
  #pragma unroll
  for (int j = 0; j < 9; ++j) { p[j] = pr[tid + j*256]; ss += p[j]*p[j]; }
  #pragma unroll
  for (int off = 32; off > 0; off >>= 1) ss += __shfl_xor(ss, off);
  if (lane == 0) sbuf[wid] = ss;
  __syncthreads();
  float sc = rsqrtf((sbuf[0]+sbuf[1]+sbuf[2]+sbuf[3]) * (1.f/2304.f) + 1e-6f);
  float x1[9]; float ss2 = 0.f;
  #pragma unroll
  for (int j = 0; j < 9; ++j) {
    int d = tid + j*256;
    float v = xr[d] + p[j] * sc * wpost[d];
    x1[j] = v; ss2 += v*v;
    xout[(size_t)r * DMOD + d] = v;
  }
  if (wnext) {
    #pragma unroll
    for (int off = 32; off > 0; off >>= 1) ss2 += __shfl_xor(ss2, off);
    __syncthreads();                       // ensure sbuf reads above are done
    if (lane == 0) sbuf[wid] = ss2;
    __syncthreads();
    float sc2 = rsqrtf((sbuf[0]+sbuf[1]+sbuf[2]+sbuf[3]) * (1.f/2304.f) + 1e-6f);
    #pragma unroll
    for (int j = 0; j < 9; ++j) {
      int d = tid + j*256;
      hout[(size_t)r * DMOD + d] = f2bf(x1[j] * sc2 * wnext[d]);
    }
  }
}

// in-place RoPE on fp16 buffer in (B, H, S, 256) layout; one thread per (b,h,s,i<128) pair
__global__ __launch_bounds__(256) void rope_k(_Float16* __restrict__ buf, const int* __restrict__ positions,
                                              int hshift)
{
  int id = blockIdx.x * 256 + threadIdx.x;
  int i = id & 127;
  int r = id >> 7;               // (b*H + h)*S + s
  int s = r & 2047;
  int b = (r >> 11) >> hshift;
  int pos = positions[(b << 11) + s];
  float freq = __expf(-(float)i * 0.07195578415606394f);   // ln(10000)/128
  float ang = (float)pos * freq;
  float sv, cv;
  sincosf(ang, &sv, &cv);
  _Float16* p = buf + ((size_t)r << 8) + i;
  float x1 = (float)p[0], x2 = (float)p[128];
  p[0]   = (_Float16)(x1 * cv - x2 * sv);
  p[128] = (_Float16)(x2 * cv + x1 * sv);
}

// ---------------- MFMA flash attention ----------------
// 4 waves/block, 16 q-rows/wave (QTILE=64), 32-key tiles, 16x16x32 f16 MFMA.
// Swapped QK^T (mfma(K, Q^T) -> S^T) so softmax row state lives at qi=lane&15;
// P re-fragmented through a padded per-wave LDS tile; V consumed from the
// transposed (B,HKV,HD,S) buffer so PV B-fragments are contiguous 16B loads.
__global__ __launch_bounds__(256) void attn_mfma_k(const _Float16* __restrict__ qb,
                                                   const _Float16* __restrict__ kb,
                                                   const _Float16* __restrict__ vt,
                                                   const int* __restrict__ positions,
                                                   const int* __restrict__ segs,
                                                   u16* __restrict__ ob, int window)
{
  __shared__ u16 plds[4][16 * 40];   // per-wave P tile, 40-u16 row stride (80B)
  int tid = threadIdx.x;
  int lane = tid & 63, wid = tid >> 6;
  int lrow = lane & 15, quad = lane >> 4;
  int qt = blockIdx.x & 31;
  int h  = (blockIdx.x >> 5) & 7;
  int b  = blockIdx.x >> 8;
  int qbase = (qt << 6) + (wid << 4);

  const _Float16* qp = qb + ((((size_t)b * NHQ + h) * SEQ) << 8);
  const _Float16* kp = kb + ((((size_t)b * NHKV + (h >> 1)) * SEQ) << 8);
  const _Float16* vp = vt + ((((size_t)b * NHKV + (h >> 1)) * HDIM) << 11);

  // Q fragments (B-operand: col=lane&15 -> qi, k = ds*32 + quad*8 + e), live all loop
  h8v qf[8];
  #pragma unroll
  for (int ds = 0; ds < 8; ++ds)
    qf[ds] = *(const h8v*)(qp + (((size_t)(qbase + lrow)) << 8) + ds * 32 + quad * 8);

  int pos_q = positions[(b << 11) + qbase + lrow];
  int seg_q = segs[(b << 11) + qbase + lrow];

  f4v oacc[16] = {};              // D of PV: row qi = quad*4+r, col d = t*16 + lane&15
  float mi = -1e30f, li = 0.f;    // softmax state for qi = lane&15 (replicated over quads)

  int s_lo = qbase - window + 1;
  if (s_lo < 0) s_lo = 0;
  s_lo &= ~31;
  int s_hi = qbase + 15;          // inclusive; causal by index, exact mask by pos below
  u16* pl = plds[wid];

  for (int kb0 = s_lo; kb0 <= s_hi; kb0 += 32) {
    // QK^T swapped: S^T[kj][qi], kj = blk*16 + quad*4 + r, qi = lane&15
    f4v s0 = {}, s1 = {};
    #pragma unroll
    for (int ds = 0; ds < 8; ++ds) {
      h8v k0 = *(const h8v*)(kp + (((size_t)(kb0 + lrow)) << 8) + ds * 32 + quad * 8);
      h8v k1 = *(const h8v*)(kp + (((size_t)(kb0 + 16 + lrow)) << 8) + ds * 32 + quad * 8);
      s0 = __builtin_amdgcn_mfma_f32_16x16x32_f16(k0, qf[ds], s0, 0, 0, 0);
      s1 = __builtin_amdgcn_mfma_f32_16x16x32_f16(k1, qf[ds], s1, 0, 0, 0);
    }
    // softcap + mask (masked -> -3e38 so exp(masked - m) underflows to 0 even at m=-1e30)
    int kbb = (b << 11) + kb0 + (quad << 2);
    int4 pk0 = *(const int4*)(positions + kbb);
    int4 pk1 = *(const int4*)(positions + kbb + 16);
    int4 sg0 = *(const int4*)(segs + kbb);
    int4 sg1 = *(const int4*)(segs + kbb + 16);
    float lg[8];
    float mt = -3e38f;
    #pragma unroll
    for (int r = 0; r < 4; ++r) {
      float t0 = 50.f * fast_tanh(s0[r] * 0.02f);
      float t1 = 50.f * fast_tanh(s1[r] * 0.02f);
      int p0 = (&pk0.x)[r], p1 = (&pk1.x)[r];
      int g0 = (&sg0.x)[r], g1 = (&sg1.x)[r];
      bool v0 = (pos_q >= p0) && (seg_q == g0) && ((pos_q - p0) < window);
      bool v1 = (pos_q >= p1) && (seg_q == g1) && ((pos_q - p1) < window);
      lg[r]     = v0 ? t0 : -3e38f;
      lg[4 + r] = v1 ? t1 : -3e38f;
      mt = fmaxf(mt, fmaxf(lg[r], lg[4 + r]));
    }
    mt = fmaxf(mt, __shfl_xor(mt, 16));
    mt = fmaxf(mt, __shfl_xor(mt, 32));
    float mnew = fmaxf(mi, mt);
    float alpha = __expf(mi - mnew);
    mi = mnew;
    float ps = 0.f;
    u16 ph[8];
    #pragma unroll
    for (int r = 0; r < 8; ++r) {
      float p = __expf(lg[r] - mnew);
      ps += p;
      ph[r] = f2h(p);
    }
    ps += __shfl_xor(ps, 16);
    ps += __shfl_xor(ps, 32);
    li = li * alpha + ps;
    if (__any(alpha != 1.f)) {
      float a0 = __shfl(alpha, (quad << 2) + 0);
      float a1 = __shfl(alpha, (quad << 2) + 1);
      float a2 = __shfl(alpha, (quad << 2) + 2);
      float a3 = __shfl(alpha, (quad << 2) + 3);
      #pragma unroll
      for (int t = 0; t < 16; ++t) {
        oacc[t][0] *= a0; oacc[t][1] *= a1; oacc[t][2] *= a2; oacc[t][3] *= a3;
      }
    }
    // P -> LDS (row qi=lane&15, cols: blk*16 + quad*4 + {0..3}); read back as A-frag
    int wb = lrow * 40 + (quad << 2);
    *(u32*)&pl[wb]      = (u32)ph[0] | ((u32)ph[1] << 16);
    *(u32*)&pl[wb + 2]  = (u32)ph[2] | ((u32)ph[3] << 16);
    *(u32*)&pl[wb + 16] = (u32)ph[4] | ((u32)ph[5] << 16);
    *(u32*)&pl[wb + 18] = (u32)ph[6] | ((u32)ph[7] << 16);
    h8v pf = *(const h8v*)&pl[lrow * 40 + (quad << 3)];
    // PV: O[qi][d] += P[16x32] * V^T-frag[32x16] over 16 d-tiles
    #pragma unroll
    for (int t = 0; t < 16; ++t) {
      h8v vf = *(const h8v*)(vp + (((size_t)((t << 4) + lrow)) << 11) + kb0 + (quad << 3));
      oacc[t] = __builtin_amdgcn_mfma_f32_16x16x32_f16(pf, vf, oacc[t], 0, 0, 0);
    }
  }
  float linv = 1.f / li;
  float i0 = __shfl(linv, (quad << 2) + 0);
  float i1 = __shfl(linv, (quad << 2) + 1);
  float i2 = __shfl(linv, (quad << 2) + 2);
  float i3 = __shfl(linv, (quad << 2) + 3);
  #pragma unroll
  for (int t = 0; t < 16; ++t) {
    u16* op = ob + (size_t)((b << 11) + qbase + (quad << 2)) * 2048 + (h << 8) + (t << 4) + lrow;
    op[0]        = f2bf(oacc[t][0] * i0);
    op[2048]     = f2bf(oacc[t][1] * i1);
    op[2*2048]   = f2bf(oacc[t][2] * i2);
    op[3*2048]   = f2bf(oacc[t][3] * i3);
  }
}

// ---------------- driver ----------------
extern "C" void kernel_launch(void* const* d_in, const int* in_sizes, int n_in,
                              void* d_out, int out_size, void* d_ws, size_t ws_size,
                              hipStream_t stream) {
  const float* x         = (const float*)d_in[0];
  const int*   positions = (const int*)d_in[1];
  const int*   segs      = (const int*)d_in[2];
  const float* w_rms[8]  = { (const float*)d_in[3], (const float*)d_in[4], (const float*)d_in[5], (const float*)d_in[6],
                             (const float*)d_in[14], (const float*)d_in[15], (const float*)d_in[16], (const float*)d_in[17] };
  const float* wq[2]  = { (const float*)d_in[7],  (const float*)d_in[18] };
  const float* wk[2]  = { (const float*)d_in[8],  (const float*)d_in[19] };
  const float* wv[2]  = { (const float*)d_in[9],  (const float*)d_in[20] };
  const float* wo[2]  = { (const float*)d_in[10], (const float*)d_in[21] };
  const float* wi0[2] = { (const float*)d_in[11], (const float*)d_in[22] };
  const float* wi1[2] = { (const float*)d_in[12], (const float*)d_in[23] };
  const float* wom[2] = { (const float*)d_in[13], (const float*)d_in[24] };

  size_t off = 0;
  char* wsb = (char*)d_ws;
  auto alloc = [&](size_t bytes) { void* p = wsb + off; off += (bytes + 255) & ~(size_t)255; return p; };
  u16*       hbuf = (u16*)      alloc((size_t)NROWS * DMOD * 2);       // 18.9 MB
  _Float16*  qb   = (_Float16*) alloc((size_t)BATCH*NHQ*SEQ*HDIM * 2); // 16.8 MB
  _Float16*  kbv  = (_Float16*) alloc((size_t)BATCH*NHKV*SEQ*HDIM * 2);// 8.4 MB
  _Float16*  vbt  = (_Float16*) alloc((size_t)BATCH*NHKV*HDIM*SEQ * 2);// 8.4 MB (transposed V)
  u16*       obuf = (u16*)      alloc((size_t)NROWS * (NHQ*HDIM) * 2); // 16.8 MB
  float*     proj = (float*)    alloc((size_t)NROWS * DMOD * 4);       // 37.7 MB
  u16*       mbuf = (u16*)      alloc((size_t)NROWS * FDIM * 2);       // 75.5 MB
  if (off > ws_size) return;  // workspace too small; fail visibly rather than corrupt

  float* xo = (float*)d_out;

  for (int blk = 0; blk < 2; ++blk) {
    const float* pre_attn  = w_rms[blk*4 + 0];
    const float* post_attn = w_rms[blk*4 + 1];
    const float* pre_ffw   = w_rms[blk*4 + 2];
    const float* post_ffw  = w_rms[blk*4 + 3];
    const float* xin = (blk == 0) ? x : xo;
    int window = (blk == 0) ? 1024 : (1 << 30);
    const float* next_pre_attn = (blk == 0) ? w_rms[4] : nullptr;

    if (blk == 0)
      rms_bf16_k<<<NROWS, 256, 0, stream>>>(xin, pre_attn, hbuf);
    // else: previous fuse_k already produced hbuf = rms(x, pre_attn_g)

    gemm_k<1><<<32*16, 256, 0, stream>>>(hbuf, wq[blk], qb,  2048, DMOD, 0.0625f); // q, *HD^-0.5
    gemm_k<1><<<32* 8, 256, 0, stream>>>(hbuf, wk[blk], kbv, 1024, DMOD, 1.0f);
    gemm_k<2><<<32* 8, 256, 0, stream>>>(hbuf, wv[blk], vbt, 1024, DMOD, 1.0f);    // V transposed, no rope
    rope_k<<<BATCH*NHQ*SEQ*128/256, 256, 0, stream>>>(qb,  positions, 3);
    rope_k<<<BATCH*NHKV*SEQ*128/256, 256, 0, stream>>>(kbv, positions, 2);
    attn_mfma_k<<<BATCH*NHQ*(SEQ/64), 256, 0, stream>>>(qb, kbv, vbt, positions, segs, obuf, window);
    gemm_k<0><<<32*18, 256, 0, stream>>>(obuf, wo[blk], proj, DMOD, NHQ*HDIM, 1.0f);
    fuse_k<<<NROWS, 256, 0, stream>>>(proj, xin, xo, post_attn, pre_ffw, hbuf);
    gemm_dual_k<<<32*72, 256, 0, stream>>>(hbuf, wi0[blk], wi1[blk], mbuf, FDIM, DMOD);
    gemm_k<0><<<32*18, 256, 0, stream>>>(mbuf, wom[blk], proj, DMOD, FDIM, 1.0f);
    fuse_k<<<NROWS, 256, 0, stream>>>(proj, xo, xo, post_ffw, next_pre_attn, hbuf);
  }
}